// Round 8
// baseline (8375.547 us; speedup 1.0000x reference)
//
#include <hip/hip_runtime.h>
#include <hip/hip_bf16.h>
#include <math.h>

// ---------------------------------------------------------------------------
// BabiUTransformer (Universal Transformer + ACT) on gfx950.  All float I/O fp32.
// GEMMs: split-precision bf16 MFMA (hh+lh+hl, err ~2^-18 rel). Activations are
// pre-split into hi/lo bf16 planes by their PRODUCER kernels.
// r6: tap-fused conv = WIN (10.96->8.22).  r7: attn b128 rewrite = WIN (->7.82).
// r8 (this round): conv was LDS-read-BW bound (MfmaUtil 31%: 36 b128 reads per
// 72 MFMA = 512 B/MFMA vs m201's 384 at 62%).  gemm_conv now uses a 64x64
// PER-WAVE tile (4x4 frags, 2x2 waves -> 128x128 block): 48 reads / 144 MFMA
// = 341 B/MFMA (-33% LDS traffic), B staged once per 128 cols (-2x B stage),
// and conv1 gains the bijective XCD swizzle (r3: bn-pinned XCDs refetch A 8x).
// conv1 grid 1136 (8x142 chunked), conv2 568 (8x71), LDS 67.6KB, 2 blocks/CU.
// Edge zeroing by per-lane fragment masks (l==0 kills tap0, l==70 kills tap2).
// Non-conv GEMMs (gemm_s TN 64/128) and attn v2 unchanged from r7.
// ---------------------------------------------------------------------------

typedef unsigned short ushort_t;
using short8   = __attribute__((ext_vector_type(8))) short;
using floatx4  = __attribute__((ext_vector_type(4))) float;
using ushort4v = __attribute__((ext_vector_type(4))) unsigned short;

#define B_   256
#define L_   71
#define H_   512
#define M_   (B_*L_)      // 18176 rows (142 x 128); half = 9088 (71 x 128)
#define MH_  9088
#define FS_  2048
#define V_   32000
#define NH_  8
#define DK_  64

#define ATS  68           // attn q/k/v LDS row stride (floats), 272B (16B-aligned)
#define SST  72           // attn S LDS row stride (floats), 288B (16B-aligned)

__device__ inline ushort_t f2bf_rne(float f) {
    unsigned u = __float_as_uint(f);
    return (ushort_t)((u + 0x7FFFu + ((u >> 16) & 1u)) >> 16);
}

// async global->LDS, 16B per lane. LDS dest must be wave-uniform base
// (hardware writes base + lane*16); global src is per-lane.
__device__ __forceinline__ void gload16(const void* g, void* l)
{
    __builtin_amdgcn_global_load_lds(
        (__attribute__((address_space(1))) unsigned int*)(g),
        (__attribute__((address_space(3))) unsigned int*)(l),
        16, 0, 0);
}

// ---------------------------------------------------------------------------
// Tap-fused conv GEMM v2: C[m,n] = sum_d sum_c A[m-1+d, c] * B[n, d*C + c]
// A planes [rows, C=lda]; B planes [N, 3*lda].  TM=128, TN=128, 4 waves 2x2,
// each wave 64x64 (4x4 frags x 3 taps x 3 split = 144 MFMA / K-step,
// 48 ds_read_b128 -> 341 B/MFMA).  A slab 144 rows staged (130 used, 9 units);
// B: 3 taps x 8 groups = 24 units.  LDS 67.6 KB -> 2 blocks/CU.
// MODE 0 (conv1): bias+relu -> bf16 hi/lo out.  Grid 1136 = 8 XCD x 142.
// MODE 1 (conv2): f32 partial -> Cpart + z*partStride. Grid 568 = 8 XCD x 71.
// Both grids 1-D with bijective chunked XCD decode (contiguous by per XCD).
// ---------------------------------------------------------------------------
template<int MODE>
__global__ __launch_bounds__(256) void gemm_conv(
    const ushort_t* __restrict__ AH, const ushort_t* __restrict__ AL,
    int lda, int rowA, int rowG,
    const ushort_t* __restrict__ Bh, const ushort_t* __restrict__ Bl,
    int N, const float* __restrict__ bias,
    ushort_t* __restrict__ CoutH, ushort_t* __restrict__ CoutL,
    float* __restrict__ Cpart, long partStride, int cLen)
{
    __shared__ __attribute__((aligned(16))) short Ahs[4608], Als[4608];
    __shared__ __attribute__((aligned(16))) short Bhs[12288], Bls[12288];

    const int tid  = threadIdx.x;
    const int w    = tid >> 6, lane = tid & 63;

    int bn, by, z;
    if (MODE == 1) {
        // 568 = 8 x 71; logical l = xcd*71 + k; by-major, members (z,bn)
        const int id = blockIdx.x;
        const int l  = (id & 7) * 71 + (id >> 3);
        by = l >> 3;
        const int mem = l & 7;
        z  = mem >> 2;
        bn = mem & 3;
    } else {
        // 1136 = 8 x 142; by-major, 16 bn members per by
        const int id = blockIdx.x;
        const int l  = (id & 7) * 142 + (id >> 3);
        by = l >> 4;
        bn = l & 15;
        z  = 0;
    }
    const int cBeg = z * cLen;
    const int bm = by << 7;

    // ---- staging setup ----
    const int srow = lane & 15, skc = lane >> 4;
    const long ldb = 3L * lda;
    // A units u in {w, w+4} (+ u=8 for wave 0); slab row 0 = global bm-1
    const long aOff0 = (long)(rowA + bm - 1 + (w    ) * 16 + srow) * lda + skc * 8;
    const long aOff1 = (long)(rowA + bm - 1 + (w + 4) * 16 + srow) * lda + skc * 8;
    const long aOff2 = (long)(rowA + bm - 1 + 128 + srow) * lda + skc * 8;  // u=8
    // B units u = d*8+g, u in {w, w+4, ..., w+20}
    long bOffs[6];
    #pragma unroll
    for (int t = 0; t < 6; t++) {
        const int u = w + 4 * t;
        const int d = u >> 3, g = u & 7;
        bOffs[t] = (long)(bn * 128 + g * 16 + srow) * ldb + (long)d * lda + skc * 8;
    }

    // ---- fragment read offsets ----
    const int quad = lane >> 4, mr = lane & 15;
    const int wr = w >> 1, wc = w & 1;    // wave quadrant in 2x2
    int aoffs[4][3];
    bool am0[4], am2[4];
    #pragma unroll
    for (int i = 0; i < 4; i++) {
        #pragma unroll
        for (int d = 0; d < 3; d++) {
            const int s = wr * 64 + i * 16 + mr + d;   // slab row 0..129
            aoffs[i][d] = (s >> 4) * 512 + quad * 128 + (s & 15) * 8;
        }
        const int lm = (bm + wr * 64 + i * 16 + mr + rowG) % 71;
        am0[i] = (lm == 0);
        am2[i] = (lm == 70);
    }

    floatx4 acc[4][4] = {};

    const int cEnd = cBeg + cLen;
    for (int c0 = cBeg; c0 < cEnd; c0 += 32) {
        __syncthreads();   // previous step's ds_reads done before overwrite
        gload16(AH + aOff0 + c0, Ahs + (w    ) * 512);
        gload16(AH + aOff1 + c0, Ahs + (w + 4) * 512);
        gload16(AL + aOff0 + c0, Als + (w    ) * 512);
        gload16(AL + aOff1 + c0, Als + (w + 4) * 512);
        if (w == 0) {
            gload16(AH + aOff2 + c0, Ahs + 8 * 512);
            gload16(AL + aOff2 + c0, Als + 8 * 512);
        }
        #pragma unroll
        for (int t = 0; t < 6; t++) {
            const int u = w + 4 * t;
            gload16(Bh + bOffs[t] + c0, Bhs + u * 512);
            gload16(Bl + bOffs[t] + c0, Bls + u * 512);
        }
        __syncthreads();   // loads landed (compiler drains vmcnt here)

        #pragma unroll
        for (int d = 0; d < 3; d++) {
            short8 bhf[4], blf[4];
            #pragma unroll
            for (int j = 0; j < 4; j++) {
                const int bo = (d * 8 + wc * 4 + j) * 512 + quad * 128 + mr * 8;
                bhf[j] = *(const short8*)(Bhs + bo);
                blf[j] = *(const short8*)(Bls + bo);
            }
            #pragma unroll
            for (int i = 0; i < 4; i++) {
                short8 a_h = *(const short8*)(Ahs + aoffs[i][d]);
                short8 a_l = *(const short8*)(Als + aoffs[i][d]);
                if (d == 0) { if (am0[i]) { a_h = (short8)0; a_l = (short8)0; } }
                if (d == 2) { if (am2[i]) { a_h = (short8)0; a_l = (short8)0; } }
                #pragma unroll
                for (int j = 0; j < 4; j++) {
                    acc[i][j] = __builtin_amdgcn_mfma_f32_16x16x32_bf16(a_h, bhf[j], acc[i][j], 0, 0, 0);
                    acc[i][j] = __builtin_amdgcn_mfma_f32_16x16x32_bf16(a_l, bhf[j], acc[i][j], 0, 0, 0);
                    acc[i][j] = __builtin_amdgcn_mfma_f32_16x16x32_bf16(a_h, blf[j], acc[i][j], 0, 0, 0);
                }
            }
        }
    }

    // C/D layout: col = lane&15, row = quad*4 + r
    #pragma unroll
    for (int j = 0; j < 4; j++) {
        const int gcol = bn * 128 + wc * 64 + j * 16 + mr;
        const float bv = (MODE == 0) ? bias[gcol] : 0.f;
        #pragma unroll
        for (int i = 0; i < 4; i++) {
            #pragma unroll
            for (int r = 0; r < 4; r++) {
                const int grow = bm + wr * 64 + i * 16 + quad * 4 + r;
                float v = acc[i][j][r];
                if (MODE == 0) {
                    v = fmaxf(v + bv, 0.f);
                    const long cidx = (long)grow * N + gcol;
                    ushort_t h = f2bf_rne(v);
                    float hf = __uint_as_float(((unsigned)h) << 16);
                    CoutH[cidx] = h;
                    CoutL[cidx] = f2bf_rne(v - hf);
                } else {
                    Cpart[(long)z * partStride + (long)grow * N + gcol] = v;
                }
            }
        }
    }
}

// ---------------------------------------------------------------------------
// Split GEMM (non-conv, unchanged from r7)
// ---------------------------------------------------------------------------
template<int TN>
__global__ __launch_bounds__(256) void gemm_s(
    const ushort_t* __restrict__ AH, const ushort_t* __restrict__ AL,
    int lda, int rowA,
    const ushort_t* __restrict__ Bh, const ushort_t* __restrict__ Bl,
    int N, int K,
    const float* __restrict__ bias, const float* residual,
    float alpha, int rowC, int outMode,
    float* Cout, ushort_t* CoutH, ushort_t* CoutL)
{
    constexpr int AF = (TN == 128) ? 4 : 2;   // a-frags per wave
    __shared__ __attribute__((aligned(16))) short Ahs[4096], Als[4096];
    __shared__ __attribute__((aligned(16))) short Bhs[TN * 32], Bls[TN * 32];

    const int tid  = threadIdx.x;
    const int w    = tid >> 6, lane = tid & 63;
    const int bm = blockIdx.y << 7, bn = blockIdx.x * TN;

    const int srow = lane & 15;
    const int skc  = lane >> 4;
    const int ra0  = w * 16 + srow;
    const int ra1  = ra0 + 64;
    const ushort_t* pAh0 = AH + (long)(bm + ra0 + rowA) * lda + skc * 8;
    const ushort_t* pAl0 = AL + (long)(bm + ra0 + rowA) * lda + skc * 8;
    const ushort_t* pAh1 = AH + (long)(bm + ra1 + rowA) * lda + skc * 8;
    const ushort_t* pAl1 = AL + (long)(bm + ra1 + rowA) * lda + skc * 8;
    const ushort_t* pBh0 = Bh + (long)(bn + ra0) * K + skc * 8;
    const ushort_t* pBl0 = Bl + (long)(bn + ra0) * K + skc * 8;
    const ushort_t* pBh1 = (TN == 128) ? (Bh + (long)(bn + ra1) * K + skc * 8) : nullptr;
    const ushort_t* pBl1 = (TN == 128) ? (Bl + (long)(bn + ra1) * K + skc * 8) : nullptr;

    const int quad = lane >> 4, mr = lane & 15;
    const int wrM   = (TN == 128) ? ((w >> 1) << 6) : (w << 5);
    const int wcN   = (TN == 128) ? ((w & 1) << 6) : 0;
    const int agrp0 = (TN == 128) ? ((w >> 1) << 2) : (w << 1);
    const int bgrp0 = (TN == 128) ? ((w & 1) << 2) : 0;
    const int foff  = quad * 128 + mr * 8;

    floatx4 acc[AF][4] = {};

    for (int k0 = 0; k0 < K; k0 += 32) {
        __syncthreads();
        gload16(pAh0 + k0, Ahs + w * 512);
        gload16(pAh1 + k0, Ahs + (w + 4) * 512);
        gload16(pAl0 + k0, Als + w * 512);
        gload16(pAl1 + k0, Als + (w + 4) * 512);
        if constexpr (TN == 128) {
            gload16(pBh0 + k0, Bhs + w * 512);
            gload16(pBh1 + k0, Bhs + (w + 4) * 512);
            gload16(pBl0 + k0, Bls + w * 512);
            gload16(pBl1 + k0, Bls + (w + 4) * 512);
        } else {
            gload16(pBh0 + k0, Bhs + w * 512);
            gload16(pBl0 + k0, Bls + w * 512);
        }
        __syncthreads();

        short8 ah[AF], al[AF], bh[4], bl[4];
        #pragma unroll
        for (int i = 0; i < AF; i++) {
            ah[i] = *(const short8*)(Ahs + (agrp0 + i) * 512 + foff);
            al[i] = *(const short8*)(Als + (agrp0 + i) * 512 + foff);
        }
        #pragma unroll
        for (int j = 0; j < 4; j++) {
            bh[j] = *(const short8*)(Bhs + (bgrp0 + j) * 512 + foff);
            bl[j] = *(const short8*)(Bls + (bgrp0 + j) * 512 + foff);
        }
        #pragma unroll
        for (int i = 0; i < AF; i++)
        #pragma unroll
        for (int j = 0; j < 4; j++) {
            acc[i][j] = __builtin_amdgcn_mfma_f32_16x16x32_bf16(ah[i], bh[j], acc[i][j], 0, 0, 0);
            acc[i][j] = __builtin_amdgcn_mfma_f32_16x16x32_bf16(al[i], bh[j], acc[i][j], 0, 0, 0);
            acc[i][j] = __builtin_amdgcn_mfma_f32_16x16x32_bf16(ah[i], bl[j], acc[i][j], 0, 0, 0);
        }
    }

    #pragma unroll
    for (int j = 0; j < 4; j++) {
        const int gcol = bn + wcN + j * 16 + mr;
        const float bv = bias ? bias[gcol] : 0.f;
        #pragma unroll
        for (int i = 0; i < AF; i++) {
            #pragma unroll
            for (int r = 0; r < 4; r++) {
                const int grow = bm + wrM + i * 16 + quad * 4 + r;
                const long crow = (long)grow + rowC;
                float v = acc[i][j][r] * alpha + bv;
                if (residual) v += residual[crow * N + gcol];
                const long cidx = crow * (long)N + gcol;
                if (outMode == 2) {
                    ushort_t h = f2bf_rne(v);
                    float hf = __uint_as_float(((unsigned)h) << 16);
                    CoutH[cidx] = h;
                    CoutL[cidx] = f2bf_rne(v - hf);
                } else {
                    Cout[cidx] = v;
                }
            }
        }
    }
}

// split-K=2 reduce for conv2: v = p0+p1+bias+trunk; trunk=v; prev update.
__global__ __launch_bounds__(256) void conv2_reduce(
    const float* __restrict__ part, long partStride,
    const float* __restrict__ bias, float* __restrict__ trunk,
    float* __restrict__ prev, const float* __restrict__ uw, int rowC)
{
    const long n4 = (long)MH_ * H_ / 4;
    long i4 = (long)blockIdx.x * 256 + threadIdx.x;
    if (i4 >= n4) return;
    const long row  = i4 >> 7;            // 0..9087 (128 float4 per row)
    const float4 p0 = ((const float4*)part)[i4];
    const float4 p1 = ((const float4*)(part + partStride))[i4];
    const float4 b4 = ((const float4*)bias)[i4 & 127];
    const long  ti  = (long)rowC * 128 + i4;
    float4 tv = ((const float4*)trunk)[ti];
    float4 v;
    v.x = p0.x + p1.x + b4.x + tv.x;
    v.y = p0.y + p1.y + b4.y + tv.y;
    v.z = p0.z + p1.z + b4.z + tv.z;
    v.w = p0.w + p1.w + b4.w + tv.w;
    ((float4*)trunk)[ti] = v;
    const float u = uw[rowC + row];
    float4 pv = ((const float4*)prev)[ti];
    pv.x = v.x * u + pv.x * (1.f - u);
    pv.y = v.y * u + pv.y * (1.f - u);
    pv.z = v.z * u + pv.z * (1.f - u);
    pv.w = v.w * u + pv.w * (1.f - u);
    ((float4*)prev)[ti] = pv;
}

// Timing-signal tables, float32 math (matches numpy float32 exp/sin chain).
__global__ __launch_bounds__(256) void sig_prep(float* __restrict__ T, float* __restrict__ P)
{
    int i = blockIdx.x * 256 + threadIdx.x;
    const int NT = 71 * 512;
    if (i >= NT + 6 * 512) return;
    int pos, c, idx;
    float* dst;
    if (i < NT) { pos = i >> 9; c = i & 511; dst = T; idx = i; }
    else        { int j = i - NT; pos = j >> 9; c = j & 511; dst = P; idx = j; }
    const float loginc = 0.036119766f;
    int jj = c & 255;
    float inv = expf(-(float)jj * loginc);
    float arg = (float)pos * inv;
    dst[idx] = (c < 256) ? sinf(arg) : cosf(arg);
}

// active-gate: flag |= any(hp<0.9 && nu<6)   (ballot, 1 atomic/wave)
__global__ __launch_bounds__(256) void gate_kernel(
    const float* __restrict__ hp, const float* __restrict__ nu, int* __restrict__ flag)
{
    int i = blockIdx.x * 256 + threadIdx.x;
    bool act = (i < M_) && (hp[i] < 0.9f) && (nu[i] < 6.0f);
    unsigned long long b = __ballot(act);
    if ((threadIdx.x & 63) == 0 && b) atomicOr(flag, 1);
}

// s = state + T[l] + P[t] (in-place); pr = sigmoid(s.p_w+p_b); gated ACT.
__global__ __launch_bounds__(256) void s_pr_kernel(
    float* trunk, const float* __restrict__ Ttab, const float* __restrict__ Ptab,
    const float* __restrict__ p_w, const float* __restrict__ p_b,
    float* __restrict__ hp, float* __restrict__ rem, float* __restrict__ nu,
    float* __restrict__ uw, const int* __restrict__ flag, int t)
{
    const int row  = blockIdx.x * 4 + (threadIdx.x >> 6);
    const int lane = threadIdx.x & 63;
    const int l    = row % 71;
    float dot = 0.f;
    #pragma unroll
    for (int j = 0; j < 8; j++) {
        int c  = lane + 64 * j;
        float sv = trunk[(long)row * H_ + c] + Ttab[l * H_ + c] + Ptab[t * H_ + c];
        trunk[(long)row * H_ + c] = sv;
        dot += sv * p_w[c];
    }
    #pragma unroll
    for (int o = 32; o; o >>= 1) dot += __shfl_xor(dot, o);
    if (lane == 0) {
        if (flag[0]) {
            float pr = 1.f / (1.f + expf(-(dot + p_b[0])));
            float hp0 = hp[row], rem0 = rem[row], nu0 = nu[row];
            float still = (hp0 < 1.0f) ? 1.f : 0.f;
            float tot   = hp0 + pr * still;
            float nh    = ((tot > 0.9f) ? 1.f : 0.f) * still;
            float st2   = ((tot <= 0.9f) ? 1.f : 0.f) * still;
            float hp2   = hp0 + pr * st2;
            float rem2  = rem0 + nh * (1.f - hp2);
            hp2 += nh * rem2;
            hp[row] = hp2; rem[row] = rem2; nu[row] = nu0 + st2 + nh;
            uw[row] = pr * st2 + nh * rem2;
        } else {
            uw[row] = 0.f;
        }
    }
}

// LayerNorm fp32 -> bf16 hi/lo planes.
__global__ __launch_bounds__(256) void ln_kernel(
    const float* __restrict__ X, const float* __restrict__ g,
    const float* __restrict__ bb, ushort_t* __restrict__ outH,
    ushort_t* __restrict__ outL)
{
    const int row  = blockIdx.x * 4 + (threadIdx.x >> 6);
    const int lane = threadIdx.x & 63;
    const float* xr = X + (long)row * H_;
    float v[8];
    float s = 0.f;
    #pragma unroll
    for (int j = 0; j < 8; j++) { v[j] = xr[lane + 64 * j]; s += v[j]; }
    #pragma unroll
    for (int o = 32; o; o >>= 1) s += __shfl_xor(s, o);
    float mean = s * (1.f / 512.f);
    float q = 0.f;
    #pragma unroll
    for (int j = 0; j < 8; j++) { float d = v[j] - mean; q += d * d; }
    #pragma unroll
    for (int o = 32; o; o >>= 1) q += __shfl_xor(q, o);
    float sd  = sqrtf(q * (1.f / 511.f));
    float inv = 1.f / (sd + 1e-6f);
    #pragma unroll
    for (int j = 0; j < 8; j++) {
        int c = lane + 64 * j;
        float val = g[c] * (v[j] - mean) * inv + bb[c];
        ushort_t h = f2bf_rne(val);
        float hf = __uint_as_float(((unsigned)h) << 16);
        long idx = (long)row * H_ + c;
        outH[idx] = h;
        outL[idx] = f2bf_rne(val - hf);
    }
}

// ---------------------------------------------------------------------------
// Attention v2 (unchanged from r7), fp32, LDS-b128 vectorized.
// ---------------------------------------------------------------------------
__global__ __launch_bounds__(256) void attn_kernel(
    const float* __restrict__ qkv, ushort_t* __restrict__ ctxH,
    ushort_t* __restrict__ ctxL)
{
    __shared__ __attribute__((aligned(16))) float qs[L_ * ATS];        // 19312 B
    __shared__ __attribute__((aligned(16))) float ks[(L_ + 1) * ATS];  // 19584 B (V reuses)
    __shared__ __attribute__((aligned(16))) float Ss[L_ * SST];        // 20448 B
    __shared__ float rsum[L_ + 1];
    const int tid = threadIdx.x;
    const int b = blockIdx.x >> 3, h = blockIdx.x & 7;
    const long qbase = (long)b * L_ * 1536 + h * DK_;

    // ---- stage Q,K (float4); zero K row 71 ----
    for (int idx = tid; idx < L_ * 16; idx += 256) {
        const int i = idx >> 4, s4 = idx & 15;
        const float4 qv = *(const float4*)(qkv + qbase + (long)i * 1536 + 4 * s4);
        const float4 kv = *(const float4*)(qkv + qbase + 512 + (long)i * 1536 + 4 * s4);
        *(float4*)(qs + i * ATS + 4 * s4) = qv;
        *(float4*)(ks + i * ATS + 4 * s4) = kv;
    }
    if (tid < 16) {
        float4 zz = {0.f, 0.f, 0.f, 0.f};
        *(float4*)(ks + 71 * ATS + 4 * tid) = zz;
    }
    __syncthreads();

    // ---- QK^T: 18 j-quads x 71 rows = 1278 items ----
    for (int item = tid; item < 18 * L_; item += 256) {
        const int jq = item / 71, i = item - jq * 71;
        const float* qr = qs + i * ATS;
        const float* k0 = ks + (4 * jq) * ATS;
        float s0 = 0.f, s1 = 0.f, s2 = 0.f, s3 = 0.f;
        #pragma unroll
        for (int s4 = 0; s4 < 16; s4++) {
            const float4 qv = *(const float4*)(qr + 4 * s4);
            const float4 k0v = *(const float4*)(k0 + 4 * s4);
            const float4 k1v = *(const float4*)(k0 + ATS + 4 * s4);
            const float4 k2v = *(const float4*)(k0 + 2 * ATS + 4 * s4);
            const float4 k3v = *(const float4*)(k0 + 3 * ATS + 4 * s4);
            s0 += qv.x * k0v.x + qv.y * k0v.y + qv.z * k0v.z + qv.w * k0v.w;
            s1 += qv.x * k1v.x + qv.y * k1v.y + qv.z * k1v.z + qv.w * k1v.w;
            s2 += qv.x * k2v.x + qv.y * k2v.y + qv.z * k2v.z + qv.w * k2v.w;
            s3 += qv.x * k3v.x + qv.y * k3v.y + qv.z * k3v.z + qv.w * k3v.w;
        }
        float4 sv; sv.x = s0; sv.y = s1; sv.z = s2; sv.w = s3;
        *(float4*)(Ss + i * SST + 4 * jq) = sv;
    }
    __syncthreads();

    // ---- re-stage V into ks (rows 0..70; row 71 stays zero) ----
    for (int idx = tid; idx < L_ * 16; idx += 256) {
        const int i = idx >> 4, s4 = idx & 15;
        *(float4*)(ks + i * ATS + 4 * s4) =
            *(const float4*)(qkv + qbase + 1024 + (long)i * 1536 + 4 * s4);
    }

    // ---- softmax: 4 lanes per row; rows {g, g+64}; deferred normalization ----
    {
        const int g = tid >> 2, r = tid & 3;
        #pragma unroll
        for (int half = 0; half < 2; half++) {
            const int row = g + half * 64;
            if (row < L_) {
                float4 vals[5];
                float mx = -1e30f;
                #pragma unroll
                for (int t = 0; t < 5; t++) {
                    const int q = r + 4 * t;
                    if (q < 18) {
                        float4 v = *(const float4*)(Ss + row * SST + 4 * q);
                        if (q == 17) v.w = -1e30f;   // j = 71 pad
                        vals[t] = v;
                        mx = fmaxf(mx, fmaxf(fmaxf(v.x, v.y), fmaxf(v.z, v.w)));
                    }
                }
                mx = fmaxf(mx, __shfl_xor(mx, 1));
                mx = fmaxf(mx, __shfl_xor(mx, 2));
                float sm = 0.f;
                #pragma unroll
                for (int t = 0; t < 5; t++) {
                    const int q = r + 4 * t;
                    if (q < 18) {
                        float4 v = vals[t];
                        v.x = expf(v.x - mx); v.y = expf(v.y - mx);
                        v.z = expf(v.z - mx); v.w = expf(v.w - mx);
                        sm += v.x + v.y + v.z + v.w;
                        *(float4*)(Ss + row * SST + 4 * q) = v;
                    }
                }
                sm += __shfl_xor(sm, 1);
                sm += __shfl_xor(sm, 2);
                if (r == 0) rsum[row] = 1.f / sm;
            }
        }
    }
    __syncthreads();

    // ---- PV: item (i,dq) -> ctx[i][4dq..+3] ----
    const long obase = (long)b * L_ * H_ + h * DK_;
    for (int item = tid; item < L_ * 16; item += 256) {
        const int i = item >> 4, dq = item & 15;
        const float* sr = Ss + i * SST;
        float ax = 0.f, ay = 0.f, az = 0.f, aw = 0.f;
        #pragma unroll
        for (int jq = 0; jq < 18; jq++) {
            const float4 sv = *(const float4*)(sr + 4 * jq);
            const float* v0 = ks + (4 * jq) * ATS + 4 * dq;
            const float4 va = *(const float4*)(v0);
            const float4 vb = *(const float4*)(v0 + ATS);
            const float4 vc = *(const float4*)(v0 + 2 * ATS);
            const float4 vd = *(const float4*)(v0 + 3 * ATS);
            ax += sv.x * va.x + sv.y * vb.x + sv.z * vc.x + sv.w * vd.x;
            ay += sv.x * va.y + sv.y * vb.y + sv.z * vc.y + sv.w * vd.y;
            az += sv.x * va.z + sv.y * vb.z + sv.z * vc.z + sv.w * vd.z;
            aw += sv.x * va.w + sv.y * vb.w + sv.z * vc.w + sv.w * vd.w;
        }
        const float rs = rsum[i];
        float o[4] = {ax * rs, ay * rs, az * rs, aw * rs};
        ushort4v hv, lv;
        #pragma unroll
        for (int c = 0; c < 4; c++) {
            ushort_t hh = f2bf_rne(o[c]);
            float hf = __uint_as_float(((unsigned)hh) << 16);
            hv[c] = hh;
            lv[c] = f2bf_rne(o[c] - hf);
        }
        const long oo = obase + (long)i * H_ + 4 * dq;
        *(ushort4v*)(ctxH + oo) = hv;
        *(ushort4v*)(ctxL + oo) = lv;
    }
}

// Embedding -> bf16 hi/lo planes
__global__ __launch_bounds__(256) void embed_kernel(
    const int* __restrict__ story, const int* __restrict__ query,
    const float* __restrict__ emb, const float* __restrict__ mask,
    ushort_t* __restrict__ xH, ushort_t* __restrict__ xL)
{
    __shared__ int idx[11];
    const int row = blockIdx.x;
    const int b = row / 71, m = row % 71;
    const int tid = threadIdx.x;
    if (tid < 11)
        idx[tid] = (m < 70) ? story[((long)b * 70 + m) * 11 + tid]
                            : query[(long)b * 11 + tid];
    __syncthreads();
    for (int c = tid; c < H_; c += 256) {
        float acc = 0.f;
        #pragma unroll
        for (int s = 0; s < 11; s++)
            acc += emb[(long)idx[s] * H_ + c] * mask[s * H_ + c];
        ushort_t h = f2bf_rne(acc);
        float hf = __uint_as_float(((unsigned)h) << 16);
        long o = (long)row * H_ + c;
        xH[o] = h;
        xL[o] = f2bf_rne(acc - hf);
    }
}

// transpose + scale + split fp32 [R,C] -> bf16 hi/lo planes rows rowOff.., ld=R
__global__ __launch_bounds__(256) void wsplitT_kernel(
    const float* __restrict__ in, ushort_t* __restrict__ hi, ushort_t* __restrict__ lo,
    int R, int C, int rowOff, float scale)
{
    long i = (long)blockIdx.x * 256 + threadIdx.x;
    if (i < (long)R * C) {
        int r = (int)(i / C), c = (int)(i % C);
        float f = in[i] * scale;
        ushort_t h = f2bf_rne(f);
        float hf = __uint_as_float(((unsigned)h) << 16);
        hi[(long)(c + rowOff) * R + r] = h;
        lo[(long)(c + rowOff) * R + r] = f2bf_rne(f - hf);
    }
}

// conv weight gather+split: plane[n*(3C) + d*C + c] = w[(n*C + c)*3 + d]
__global__ __launch_bounds__(256) void convw_split_kernel(
    const float* __restrict__ w, ushort_t* __restrict__ hi, ushort_t* __restrict__ lo,
    int N, int C)
{
    long i = (long)blockIdx.x * 256 + threadIdx.x;
    if (i < (long)N * C * 3) {
        int n = (int)(i / (3 * C));
        int r = (int)(i % (3 * C));
        int d = r / C, c = r % C;
        float f = w[((long)n * C + c) * 3 + d];
        ushort_t h = f2bf_rne(f);
        float hf = __uint_as_float(((unsigned)h) << 16);
        hi[i] = h;
        lo[i] = f2bf_rne(f - hf);
    }
}

// plain split: emb [V,E] -> hi/lo planes same layout
__global__ __launch_bounds__(256) void esplit_kernel(
    const float* __restrict__ in, ushort_t* __restrict__ hi, ushort_t* __restrict__ lo,
    long n)
{
    long i = (long)blockIdx.x * 256 + threadIdx.x;
    if (i < n) {
        float f = in[i];
        ushort_t h = f2bf_rne(f);
        float hf = __uint_as_float(((unsigned)h) << 16);
        hi[i] = h;
        lo[i] = f2bf_rne(f - hf);
    }
}

__global__ __launch_bounds__(256) void zero_f32(float* __restrict__ p, long n)
{
    long i = (long)blockIdx.x * 256 + threadIdx.x;
    if (i < n) p[i] = 0.f;
}

// pooled[b,c] = (sum_l prev[b,l,c]) / 71 -> bf16 hi/lo planes
__global__ __launch_bounds__(256) void pooled_kernel(
    const float* __restrict__ prev, ushort_t* __restrict__ pH, ushort_t* __restrict__ pL)
{
    int i = blockIdx.x * 256 + threadIdx.x;   // [0, 256*512)
    int b = i >> 9, c = i & 511;
    float s = 0.f;
    for (int l = 0; l < L_; l++) s += prev[((long)b * L_ + l) * H_ + c];
    float p = s / 71.0f;
    ushort_t h = f2bf_rne(p);
    float hf = __uint_as_float(((unsigned)h) << 16);
    pH[i] = h;
    pL[i] = f2bf_rne(p - hf);
}

__global__ __launch_bounds__(256) void softmax_kernel(
    const float* __restrict__ ah, float* __restrict__ out)
{
    __shared__ float red[256];
    const int b = blockIdx.x, tid = threadIdx.x;
    const float* a = ah + (long)b * V_;
    float mx = -1e30f;
    for (int i = tid; i < V_; i += 256) mx = fmaxf(mx, a[i]);
    red[tid] = mx; __syncthreads();
    for (int o = 128; o; o >>= 1) { if (tid < o) red[tid] = fmaxf(red[tid], red[tid + o]); __syncthreads(); }
    mx = red[0]; __syncthreads();
    float s = 0.f;
    for (int i = tid; i < V_; i += 256) s += expf(a[i] - mx);
    red[tid] = s; __syncthreads();
    for (int o = 128; o; o >>= 1) { if (tid < o) red[tid] += red[tid + o]; __syncthreads(); }
    float inv = 1.f / red[0];
    float* o_ = out + (long)b * V_;
    for (int i = tid; i < V_; i += 256) o_[i] = expf(a[i] - mx) * inv;
}

__global__ __launch_bounds__(256) void tails_kernel(
    const float* __restrict__ rem, const float* __restrict__ nu, float* __restrict__ out)
{
    int i = blockIdx.x * 256 + threadIdx.x;
    if (i < M_) {
        out[i] = rem[i];
        out[M_ + i] = nu[i];
    }
}

// ---------------------------------------------------------------------------
extern "C" void kernel_launch(void* const* d_in, const int* in_sizes, int n_in,
                              void* d_out, int out_size, void* d_ws, size_t ws_size,
                              hipStream_t stream)
{
    const int*   story  = (const int*)d_in[0];
    const int*   query  = (const int*)d_in[1];
    const float* emb    = (const float*)d_in[2];
    const float* mask_p = (const float*)d_in[3];
    const float* proj_w = (const float*)d_in[4];
    const float* ln1_g  = (const float*)d_in[5];
    const float* ln1_b  = (const float*)d_in[6];
    const float* wq     = (const float*)d_in[7];
    const float* wk     = (const float*)d_in[8];
    const float* wv     = (const float*)d_in[9];
    const float* wo     = (const float*)d_in[10];
    const float* c1_w   = (const float*)d_in[11];
    const float* c1_b   = (const float*)d_in[12];
    const float* c2_w   = (const float*)d_in[13];
    const float* c2_b   = (const float*)d_in[14];
    const float* ln2_g  = (const float*)d_in[15];
    const float* ln2_b  = (const float*)d_in[16];
    const float* p_w    = (const float*)d_in[17];
    const float* p_b    = (const float*)d_in[18];
    const float* out_b  = (const float*)d_in[19];
    float* outp = (float*)d_out;

    char* wsb = (char*)d_ws;
    size_t off = 0;
    auto alloc = [&](size_t bytes) -> void* {
        void* p = wsb + off;
        off = (off + bytes + 255) & ~(size_t)255;
        return p;
    };
    const long ROWE = (long)M_ * H_;             // 9,306,112 elements

    float* trunkF = (float*)alloc(ROWE * 4);
    float* prevF  = (float*)alloc(ROWE * 4);
    char*  poolC  = (char*)alloc(4L * ROWE * 4); // 148.9 MB multi-purpose pool
    float* hpF    = (float*)alloc((long)M_ * 4 * 4 + 64);
    float* remF   = hpF + M_;
    float* nuF    = hpF + 2 * M_;
    float* uwF    = hpF + 3 * M_;
    int*   flags  = (int*)(hpF + 4 * M_);
    ushort_t* projH = (ushort_t*)alloc((long)H_ * H_ * 2);
    ushort_t* projL = (ushort_t*)alloc((long)H_ * H_ * 2);
    ushort_t* wqkvH = (ushort_t*)alloc((long)3 * H_ * H_ * 2);
    ushort_t* wqkvL = (ushort_t*)alloc((long)3 * H_ * H_ * 2);
    ushort_t* woH   = (ushort_t*)alloc((long)H_ * H_ * 2);
    ushort_t* woL   = (ushort_t*)alloc((long)H_ * H_ * 2);
    ushort_t* W1H   = (ushort_t*)alloc((long)FS_ * 3 * H_ * 2);
    ushort_t* W1L   = (ushort_t*)alloc((long)FS_ * 3 * H_ * 2);
    ushort_t* W2H   = (ushort_t*)alloc((long)H_ * 3 * FS_ * 2);
    ushort_t* W2L   = (ushort_t*)alloc((long)H_ * 3 * FS_ * 2);
    ushort_t* pooledH = (ushort_t*)alloc((long)B_ * H_ * 2);
    ushort_t* pooledL = (ushort_t*)alloc((long)B_ * H_ * 2);
    float* Ttab     = (float*)alloc((long)L_ * H_ * 4);
    float* Ptab     = (float*)alloc(6L * H_ * 4);

    // pool aliases (phases disjoint in time):
    ushort_t* xnH = (ushort_t*)poolC;
    ushort_t* xnL = xnH + ROWE;
    float* qkvF = (float*)(poolC + ROWE * 4);            // 3*ROWE floats
    ushort_t* ctxH = xnH;
    ushort_t* ctxL = xnL;
    ushort_t* xn2H = (ushort_t*)poolC;
    ushort_t* xn2L = xn2H + ROWE;
    ushort_t* y1H  = (ushort_t*)(poolC + ROWE * 4);
    ushort_t* y1L  = y1H + (long)MH_ * FS_;
    float* partF   = (float*)(poolC + ROWE * 4 + (long)MH_ * FS_ * 4);  // 2 x MH_*H_ f32
    ushort_t* xembH = (ushort_t*)poolC;
    ushort_t* xembL = xembH + ROWE;
    ushort_t* embH = (ushort_t*)poolC;
    ushort_t* embL = embH + (long)V_ * H_;

    dim3 blk(256);

    // --- init (ws re-poisoned every call) ---
    zero_f32<<<dim3((unsigned)((ROWE + 255) / 256)), blk, 0, stream>>>(prevF, ROWE);
    zero_f32<<<dim3((3 * M_ + 255) / 256), blk, 0, stream>>>(hpF, 3 * M_);
    zero_f32<<<dim3(1), blk, 0, stream>>>((float*)flags, 16);
    sig_prep<<<dim3(154), blk, 0, stream>>>(Ttab, Ptab);

    // --- weight prep: transpose + hi/lo split (q-scale 1/8 folded, bit-exact) ---
    wsplitT_kernel<<<dim3(1024), blk, 0, stream>>>(proj_w, projH, projL, H_, H_, 0, 1.f);
    wsplitT_kernel<<<dim3(1024), blk, 0, stream>>>(wq, wqkvH, wqkvL, H_, H_, 0, 0.125f);
    wsplitT_kernel<<<dim3(1024), blk, 0, stream>>>(wk, wqkvH, wqkvL, H_, H_, 512, 1.f);
    wsplitT_kernel<<<dim3(1024), blk, 0, stream>>>(wv, wqkvH, wqkvL, H_, H_, 1024, 1.f);
    wsplitT_kernel<<<dim3(1024), blk, 0, stream>>>(wo, woH, woL, H_, H_, 0, 1.f);
    convw_split_kernel<<<dim3(12288), blk, 0, stream>>>(c1_w, W1H, W1L, FS_, H_);
    convw_split_kernel<<<dim3(12288), blk, 0, stream>>>(c2_w, W2H, W2L, H_, FS_);

    // --- embedding + input projection ---
    embed_kernel<<<dim3(M_), blk, 0, stream>>>(story, query, emb, mask_p, xembH, xembL);
    gemm_s<64><<<dim3(H_ / 64, M_ / 128), blk, 0, stream>>>(
        xembH, xembL, H_, 0, projH, projL, H_, H_,
        nullptr, nullptr, 1.f, 0, 0, trunkF, nullptr, nullptr);

    // --- ACT loop: 6 steps with faithful any()-gate ---
    for (int t = 0; t < 6; t++) {
        gate_kernel<<<dim3(M_ / 256), blk, 0, stream>>>(hpF, nuF, flags + t);
        s_pr_kernel<<<dim3(M_ / 4), blk, 0, stream>>>(trunkF, Ttab, Ptab, p_w, p_b,
                                                      hpF, remF, nuF, uwF, flags + t, t);
        ln_kernel<<<dim3(M_ / 4), blk, 0, stream>>>(trunkF, ln1_g, ln1_b, xnH, xnL);
        gemm_s<128><<<dim3(1536 / 128, M_ / 128), blk, 0, stream>>>(
            xnH, xnL, H_, 0, wqkvH, wqkvL, 1536, H_,
            nullptr, nullptr, 1.f, 0, 0, qkvF, nullptr, nullptr);
        attn_kernel<<<dim3(B_ * NH_), blk, 0, stream>>>(qkvF, ctxH, ctxL);
        gemm_s<64><<<dim3(H_ / 64, M_ / 128), blk, 0, stream>>>(
            ctxH, ctxL, H_, 0, woH, woL, H_, H_,
            nullptr, trunkF, 1.f, 0, 0, trunkF, nullptr, nullptr);
        ln_kernel<<<dim3(M_ / 4), blk, 0, stream>>>(trunkF, ln2_g, ln2_b, xn2H, xn2L);
        for (int half = 0; half < 2; half++) {
            int ro = half * MH_;
            gemm_conv<0><<<dim3(1136), blk, 0, stream>>>(
                xn2H, xn2L, H_, ro, ro, W1H, W1L, FS_,
                c1_b, y1H, y1L, nullptr, 0, 512);
            gemm_conv<1><<<dim3(568), blk, 0, stream>>>(
                y1H, y1L, FS_, 0, ro, W2H, W2L, H_,
                nullptr, nullptr, nullptr, partF, (long)MH_ * H_, 1024);
            conv2_reduce<<<dim3((unsigned)((long)MH_ * H_ / 4 / 256)), blk, 0, stream>>>(
                partF, (long)MH_ * H_, c2_b, trunkF, prevF, uwF, ro);
        }
    }

    // --- output head ---
    pooled_kernel<<<dim3(B_ * H_ / 256), blk, 0, stream>>>(prevF, pooledH, pooledL);
    esplit_kernel<<<dim3(64000), blk, 0, stream>>>(emb, embH, embL, (long)V_ * H_);
    gemm_s<64><<<dim3(V_ / 64, B_ / 128), blk, 0, stream>>>(
        pooledH, pooledL, H_, 0, embH, embL, V_, H_,
        out_b, nullptr, 1.f, 0, 0, outp, nullptr, nullptr);
    softmax_kernel<<<dim3(B_), blk, 0, stream>>>(outp, outp + (long)B_ * V_);
    tails_kernel<<<dim3((M_ + 255) / 256), blk, 0, stream>>>(remF, nuF, outp + 2L * B_ * V_);
}

// Round 9
// 8372.710 us; speedup vs baseline: 1.0003x; 1.0003x over previous
//
#include <hip/hip_runtime.h>
#include <hip/hip_bf16.h>
#include <math.h>

// ---------------------------------------------------------------------------
// BabiUTransformer (Universal Transformer + ACT) on gfx950.  All float I/O fp32.
// GEMMs: split-precision bf16 MFMA (hh+lh+hl, err ~2^-18 rel). Activations are
// pre-split into hi/lo bf16 planes by their PRODUCER kernels.
// r6: tap-fused conv WIN (10.96->8.22). r7: attn b128 WIN (->7.82).
// r8: 128x128 conv tile REGRESSED (->8.38): LDS 67.6KB > 64KB cost block
// co-residency (occ 25->13.4%, 1 block/CU -> vmcnt drain exposed).
// EMPIRICAL RULE: static LDS > 64KB on gfx950 -> 1 block/CU.
// r9 (this round): keep the 64x64 PER-WAVE tile (341 B/MFMA, the r8 win) but
// in a 2-WAVE 128-THREAD block, TM=128 x TN=64: LDS back to 43008B (r7 level)
// -> 3 blocks/CU, drains overlap across blocks, per-block K-step is MFMA-bound
// (96 reads ~1150cy < 288 MFMA ~1400cy).  Grids: conv1 2272/half, conv2
// 1136/half, both with bijective 8-way XCD chunked decode.
// Edge zeroing by per-lane fragment masks (l==0 kills tap0, l==70 kills tap2).
// Non-conv GEMMs (gemm_s TN 64/128) and attn v2 unchanged from r7.
// ---------------------------------------------------------------------------

typedef unsigned short ushort_t;
using short8   = __attribute__((ext_vector_type(8))) short;
using floatx4  = __attribute__((ext_vector_type(4))) float;
using ushort4v = __attribute__((ext_vector_type(4))) unsigned short;

#define B_   256
#define L_   71
#define H_   512
#define M_   (B_*L_)      // 18176 rows (142 x 128); half = 9088 (71 x 128)
#define MH_  9088
#define FS_  2048
#define V_   32000
#define NH_  8
#define DK_  64

#define ATS  68           // attn q/k/v LDS row stride (floats), 272B (16B-aligned)
#define SST  72           // attn S LDS row stride (floats), 288B (16B-aligned)

__device__ inline ushort_t f2bf_rne(float f) {
    unsigned u = __float_as_uint(f);
    return (ushort_t)((u + 0x7FFFu + ((u >> 16) & 1u)) >> 16);
}

// async global->LDS, 16B per lane. LDS dest must be wave-uniform base
// (hardware writes base + lane*16); global src is per-lane.
__device__ __forceinline__ void gload16(const void* g, void* l)
{
    __builtin_amdgcn_global_load_lds(
        (__attribute__((address_space(1))) unsigned int*)(g),
        (__attribute__((address_space(3))) unsigned int*)(l),
        16, 0, 0);
}

// ---------------------------------------------------------------------------
// Tap-fused conv GEMM v3: C[m,n] = sum_d sum_c A[m-1+d, c] * B[n, d*C + c]
// A planes [rows, C=lda]; B planes [N, 3*lda].  TM=128, TN=64, 2 WAVES
// (128 threads), each wave 64x64 (4x4 frags x 3 taps x 3 split = 144 MFMA
// per K-step, 48 ds_read_b128 -> 341 B/MFMA).  A slab 144 rows (130 used,
// 9 units); B 3 taps x 4 groups = 12 units.  LDS 43008 B -> 3 blocks/CU.
// MODE 0 (conv1): bias+relu -> bf16 hi/lo out.  Grid 2272 = 8 XCD x 284.
// MODE 1 (conv2): f32 partial -> Cpart + z*partStride. Grid 1136 = 8 x 142.
// Both 1-D grids with bijective chunked XCD decode (contiguous by per XCD).
// ---------------------------------------------------------------------------
template<int MODE>
__global__ __launch_bounds__(128) void gemm_conv(
    const ushort_t* __restrict__ AH, const ushort_t* __restrict__ AL,
    int lda, int rowA, int rowG,
    const ushort_t* __restrict__ Bh, const ushort_t* __restrict__ Bl,
    int N, const float* __restrict__ bias,
    ushort_t* __restrict__ CoutH, ushort_t* __restrict__ CoutL,
    float* __restrict__ Cpart, long partStride, int cLen)
{
    __shared__ __attribute__((aligned(16))) short Ahs[4608], Als[4608];
    __shared__ __attribute__((aligned(16))) short Bhs[6144], Bls[6144];

    const int tid  = threadIdx.x;
    const int w    = tid >> 6, lane = tid & 63;   // w in {0,1}

    int bn, by, z;
    if (MODE == 1) {
        // 1136 = 8 x 142; by-major; members (z, bn) of 16 per by
        const int id = blockIdx.x;
        const int l  = (id & 7) * 142 + (id >> 3);
        by = l >> 4;
        const int mem = l & 15;
        z  = mem >> 3;
        bn = mem & 7;
    } else {
        // 2272 = 8 x 284; by-major; 32 bn members per by
        const int id = blockIdx.x;
        const int l  = (id & 7) * 284 + (id >> 3);
        by = l >> 5;
        bn = l & 31;
        z  = 0;
    }
    const int cBeg = z * cLen;
    const int bm = by << 7;

    // ---- staging setup ----
    const int srow = lane & 15, skc = lane >> 4;
    const long ldb = 3L * lda;
    // A units u in {w, w+2, w+4, w+6} (+ u=8 for wave 0); slab row 0 = bm-1
    long aOffs[4];
    #pragma unroll
    for (int t = 0; t < 4; t++) {
        const int u = w + 2 * t;
        aOffs[t] = (long)(rowA + bm - 1 + u * 16 + srow) * lda + skc * 8;
    }
    const long aOff8 = (long)(rowA + bm - 1 + 128 + srow) * lda + skc * 8;  // u=8
    // B units u = d*4+g, u in {w, w+2, ..., w+10}
    long bOffs[6];
    #pragma unroll
    for (int t = 0; t < 6; t++) {
        const int u = w + 2 * t;
        const int d = u >> 2, g = u & 3;
        bOffs[t] = (long)(bn * 64 + g * 16 + srow) * ldb + (long)d * lda + skc * 8;
    }

    // ---- fragment read offsets: wave w owns rows w*64..w*64+63 ----
    const int quad = lane >> 4, mr = lane & 15;
    int aoffs[4][3];
    bool am0[4], am2[4];
    #pragma unroll
    for (int i = 0; i < 4; i++) {
        #pragma unroll
        for (int d = 0; d < 3; d++) {
            const int s = w * 64 + i * 16 + mr + d;   // slab row 0..129
            aoffs[i][d] = (s >> 4) * 512 + quad * 128 + (s & 15) * 8;
        }
        const int lm = (bm + w * 64 + i * 16 + mr + rowG) % 71;
        am0[i] = (lm == 0);
        am2[i] = (lm == 70);
    }

    floatx4 acc[4][4] = {};

    const int cEnd = cBeg + cLen;
    for (int c0 = cBeg; c0 < cEnd; c0 += 32) {
        __syncthreads();   // previous step's ds_reads done before overwrite
        #pragma unroll
        for (int t = 0; t < 4; t++) {
            const int u = w + 2 * t;
            gload16(AH + aOffs[t] + c0, Ahs + u * 512);
            gload16(AL + aOffs[t] + c0, Als + u * 512);
        }
        if (w == 0) {
            gload16(AH + aOff8 + c0, Ahs + 8 * 512);
            gload16(AL + aOff8 + c0, Als + 8 * 512);
        }
        #pragma unroll
        for (int t = 0; t < 6; t++) {
            const int u = w + 2 * t;
            gload16(Bh + bOffs[t] + c0, Bhs + u * 512);
            gload16(Bl + bOffs[t] + c0, Bls + u * 512);
        }
        __syncthreads();   // loads landed (compiler drains vmcnt here)

        #pragma unroll
        for (int d = 0; d < 3; d++) {
            short8 bhf[4], blf[4];
            #pragma unroll
            for (int j = 0; j < 4; j++) {
                const int bo = (d * 4 + j) * 512 + quad * 128 + mr * 8;
                bhf[j] = *(const short8*)(Bhs + bo);
                blf[j] = *(const short8*)(Bls + bo);
            }
            #pragma unroll
            for (int i = 0; i < 4; i++) {
                short8 a_h = *(const short8*)(Ahs + aoffs[i][d]);
                short8 a_l = *(const short8*)(Als + aoffs[i][d]);
                if (d == 0) { if (am0[i]) { a_h = (short8)0; a_l = (short8)0; } }
                if (d == 2) { if (am2[i]) { a_h = (short8)0; a_l = (short8)0; } }
                #pragma unroll
                for (int j = 0; j < 4; j++) {
                    acc[i][j] = __builtin_amdgcn_mfma_f32_16x16x32_bf16(a_h, bhf[j], acc[i][j], 0, 0, 0);
                    acc[i][j] = __builtin_amdgcn_mfma_f32_16x16x32_bf16(a_l, bhf[j], acc[i][j], 0, 0, 0);
                    acc[i][j] = __builtin_amdgcn_mfma_f32_16x16x32_bf16(a_h, blf[j], acc[i][j], 0, 0, 0);
                }
            }
        }
    }

    // C/D layout: col = lane&15, row = quad*4 + r
    #pragma unroll
    for (int j = 0; j < 4; j++) {
        const int gcol = bn * 64 + j * 16 + mr;
        const float bv = (MODE == 0) ? bias[gcol] : 0.f;
        #pragma unroll
        for (int i = 0; i < 4; i++) {
            #pragma unroll
            for (int r = 0; r < 4; r++) {
                const int grow = bm + w * 64 + i * 16 + quad * 4 + r;
                float v = acc[i][j][r];
                if (MODE == 0) {
                    v = fmaxf(v + bv, 0.f);
                    const long cidx = (long)grow * N + gcol;
                    ushort_t h = f2bf_rne(v);
                    float hf = __uint_as_float(((unsigned)h) << 16);
                    CoutH[cidx] = h;
                    CoutL[cidx] = f2bf_rne(v - hf);
                } else {
                    Cpart[(long)z * partStride + (long)grow * N + gcol] = v;
                }
            }
        }
    }
}

// ---------------------------------------------------------------------------
// Split GEMM (non-conv, unchanged from r7)
// ---------------------------------------------------------------------------
template<int TN>
__global__ __launch_bounds__(256) void gemm_s(
    const ushort_t* __restrict__ AH, const ushort_t* __restrict__ AL,
    int lda, int rowA,
    const ushort_t* __restrict__ Bh, const ushort_t* __restrict__ Bl,
    int N, int K,
    const float* __restrict__ bias, const float* residual,
    float alpha, int rowC, int outMode,
    float* Cout, ushort_t* CoutH, ushort_t* CoutL)
{
    constexpr int AF = (TN == 128) ? 4 : 2;   // a-frags per wave
    __shared__ __attribute__((aligned(16))) short Ahs[4096], Als[4096];
    __shared__ __attribute__((aligned(16))) short Bhs[TN * 32], Bls[TN * 32];

    const int tid  = threadIdx.x;
    const int w    = tid >> 6, lane = tid & 63;
    const int bm = blockIdx.y << 7, bn = blockIdx.x * TN;

    const int srow = lane & 15;
    const int skc  = lane >> 4;
    const int ra0  = w * 16 + srow;
    const int ra1  = ra0 + 64;
    const ushort_t* pAh0 = AH + (long)(bm + ra0 + rowA) * lda + skc * 8;
    const ushort_t* pAl0 = AL + (long)(bm + ra0 + rowA) * lda + skc * 8;
    const ushort_t* pAh1 = AH + (long)(bm + ra1 + rowA) * lda + skc * 8;
    const ushort_t* pAl1 = AL + (long)(bm + ra1 + rowA) * lda + skc * 8;
    const ushort_t* pBh0 = Bh + (long)(bn + ra0) * K + skc * 8;
    const ushort_t* pBl0 = Bl + (long)(bn + ra0) * K + skc * 8;
    const ushort_t* pBh1 = (TN == 128) ? (Bh + (long)(bn + ra1) * K + skc * 8) : nullptr;
    const ushort_t* pBl1 = (TN == 128) ? (Bl + (long)(bn + ra1) * K + skc * 8) : nullptr;

    const int quad = lane >> 4, mr = lane & 15;
    const int wrM   = (TN == 128) ? ((w >> 1) << 6) : (w << 5);
    const int wcN   = (TN == 128) ? ((w & 1) << 6) : 0;
    const int agrp0 = (TN == 128) ? ((w >> 1) << 2) : (w << 1);
    const int bgrp0 = (TN == 128) ? ((w & 1) << 2) : 0;
    const int foff  = quad * 128 + mr * 8;

    floatx4 acc[AF][4] = {};

    for (int k0 = 0; k0 < K; k0 += 32) {
        __syncthreads();
        gload16(pAh0 + k0, Ahs + w * 512);
        gload16(pAh1 + k0, Ahs + (w + 4) * 512);
        gload16(pAl0 + k0, Als + w * 512);
        gload16(pAl1 + k0, Als + (w + 4) * 512);
        if constexpr (TN == 128) {
            gload16(pBh0 + k0, Bhs + w * 512);
            gload16(pBh1 + k0, Bhs + (w + 4) * 512);
            gload16(pBl0 + k0, Bls + w * 512);
            gload16(pBl1 + k0, Bls + (w + 4) * 512);
        } else {
            gload16(pBh0 + k0, Bhs + w * 512);
            gload16(pBl0 + k0, Bls + w * 512);
        }
        __syncthreads();

        short8 ah[AF], al[AF], bh[4], bl[4];
        #pragma unroll
        for (int i = 0; i < AF; i++) {
            ah[i] = *(const short8*)(Ahs + (agrp0 + i) * 512 + foff);
            al[i] = *(const short8*)(Als + (agrp0 + i) * 512 + foff);
        }
        #pragma unroll
        for (int j = 0; j < 4; j++) {
            bh[j] = *(const short8*)(Bhs + (bgrp0 + j) * 512 + foff);
            bl[j] = *(const short8*)(Bls + (bgrp0 + j) * 512 + foff);
        }
        #pragma unroll
        for (int i = 0; i < AF; i++)
        #pragma unroll
        for (int j = 0; j < 4; j++) {
            acc[i][j] = __builtin_amdgcn_mfma_f32_16x16x32_bf16(ah[i], bh[j], acc[i][j], 0, 0, 0);
            acc[i][j] = __builtin_amdgcn_mfma_f32_16x16x32_bf16(al[i], bh[j], acc[i][j], 0, 0, 0);
            acc[i][j] = __builtin_amdgcn_mfma_f32_16x16x32_bf16(ah[i], bl[j], acc[i][j], 0, 0, 0);
        }
    }

    #pragma unroll
    for (int j = 0; j < 4; j++) {
        const int gcol = bn + wcN + j * 16 + mr;
        const float bv = bias ? bias[gcol] : 0.f;
        #pragma unroll
        for (int i = 0; i < AF; i++) {
            #pragma unroll
            for (int r = 0; r < 4; r++) {
                const int grow = bm + wrM + i * 16 + quad * 4 + r;
                const long crow = (long)grow + rowC;
                float v = acc[i][j][r] * alpha + bv;
                if (residual) v += residual[crow * N + gcol];
                const long cidx = crow * (long)N + gcol;
                if (outMode == 2) {
                    ushort_t h = f2bf_rne(v);
                    float hf = __uint_as_float(((unsigned)h) << 16);
                    CoutH[cidx] = h;
                    CoutL[cidx] = f2bf_rne(v - hf);
                } else {
                    Cout[cidx] = v;
                }
            }
        }
    }
}

// split-K=2 reduce for conv2: v = p0+p1+bias+trunk; trunk=v; prev update.
__global__ __launch_bounds__(256) void conv2_reduce(
    const float* __restrict__ part, long partStride,
    const float* __restrict__ bias, float* __restrict__ trunk,
    float* __restrict__ prev, const float* __restrict__ uw, int rowC)
{
    const long n4 = (long)MH_ * H_ / 4;
    long i4 = (long)blockIdx.x * 256 + threadIdx.x;
    if (i4 >= n4) return;
    const long row  = i4 >> 7;            // 0..9087 (128 float4 per row)
    const float4 p0 = ((const float4*)part)[i4];
    const float4 p1 = ((const float4*)(part + partStride))[i4];
    const float4 b4 = ((const float4*)bias)[i4 & 127];
    const long  ti  = (long)rowC * 128 + i4;
    float4 tv = ((const float4*)trunk)[ti];
    float4 v;
    v.x = p0.x + p1.x + b4.x + tv.x;
    v.y = p0.y + p1.y + b4.y + tv.y;
    v.z = p0.z + p1.z + b4.z + tv.z;
    v.w = p0.w + p1.w + b4.w + tv.w;
    ((float4*)trunk)[ti] = v;
    const float u = uw[rowC + row];
    float4 pv = ((const float4*)prev)[ti];
    pv.x = v.x * u + pv.x * (1.f - u);
    pv.y = v.y * u + pv.y * (1.f - u);
    pv.z = v.z * u + pv.z * (1.f - u);
    pv.w = v.w * u + pv.w * (1.f - u);
    ((float4*)prev)[ti] = pv;
}

// Timing-signal tables, float32 math (matches numpy float32 exp/sin chain).
__global__ __launch_bounds__(256) void sig_prep(float* __restrict__ T, float* __restrict__ P)
{
    int i = blockIdx.x * 256 + threadIdx.x;
    const int NT = 71 * 512;
    if (i >= NT + 6 * 512) return;
    int pos, c, idx;
    float* dst;
    if (i < NT) { pos = i >> 9; c = i & 511; dst = T; idx = i; }
    else        { int j = i - NT; pos = j >> 9; c = j & 511; dst = P; idx = j; }
    const float loginc = 0.036119766f;
    int jj = c & 255;
    float inv = expf(-(float)jj * loginc);
    float arg = (float)pos * inv;
    dst[idx] = (c < 256) ? sinf(arg) : cosf(arg);
}

// active-gate: flag |= any(hp<0.9 && nu<6)   (ballot, 1 atomic/wave)
__global__ __launch_bounds__(256) void gate_kernel(
    const float* __restrict__ hp, const float* __restrict__ nu, int* __restrict__ flag)
{
    int i = blockIdx.x * 256 + threadIdx.x;
    bool act = (i < M_) && (hp[i] < 0.9f) && (nu[i] < 6.0f);
    unsigned long long b = __ballot(act);
    if ((threadIdx.x & 63) == 0 && b) atomicOr(flag, 1);
}

// s = state + T[l] + P[t] (in-place); pr = sigmoid(s.p_w+p_b); gated ACT.
__global__ __launch_bounds__(256) void s_pr_kernel(
    float* trunk, const float* __restrict__ Ttab, const float* __restrict__ Ptab,
    const float* __restrict__ p_w, const float* __restrict__ p_b,
    float* __restrict__ hp, float* __restrict__ rem, float* __restrict__ nu,
    float* __restrict__ uw, const int* __restrict__ flag, int t)
{
    const int row  = blockIdx.x * 4 + (threadIdx.x >> 6);
    const int lane = threadIdx.x & 63;
    const int l    = row % 71;
    float dot = 0.f;
    #pragma unroll
    for (int j = 0; j < 8; j++) {
        int c  = lane + 64 * j;
        float sv = trunk[(long)row * H_ + c] + Ttab[l * H_ + c] + Ptab[t * H_ + c];
        trunk[(long)row * H_ + c] = sv;
        dot += sv * p_w[c];
    }
    #pragma unroll
    for (int o = 32; o; o >>= 1) dot += __shfl_xor(dot, o);
    if (lane == 0) {
        if (flag[0]) {
            float pr = 1.f / (1.f + expf(-(dot + p_b[0])));
            float hp0 = hp[row], rem0 = rem[row], nu0 = nu[row];
            float still = (hp0 < 1.0f) ? 1.f : 0.f;
            float tot   = hp0 + pr * still;
            float nh    = ((tot > 0.9f) ? 1.f : 0.f) * still;
            float st2   = ((tot <= 0.9f) ? 1.f : 0.f) * still;
            float hp2   = hp0 + pr * st2;
            float rem2  = rem0 + nh * (1.f - hp2);
            hp2 += nh * rem2;
            hp[row] = hp2; rem[row] = rem2; nu[row] = nu0 + st2 + nh;
            uw[row] = pr * st2 + nh * rem2;
        } else {
            uw[row] = 0.f;
        }
    }
}

// LayerNorm fp32 -> bf16 hi/lo planes.
__global__ __launch_bounds__(256) void ln_kernel(
    const float* __restrict__ X, const float* __restrict__ g,
    const float* __restrict__ bb, ushort_t* __restrict__ outH,
    ushort_t* __restrict__ outL)
{
    const int row  = blockIdx.x * 4 + (threadIdx.x >> 6);
    const int lane = threadIdx.x & 63;
    const float* xr = X + (long)row * H_;
    float v[8];
    float s = 0.f;
    #pragma unroll
    for (int j = 0; j < 8; j++) { v[j] = xr[lane + 64 * j]; s += v[j]; }
    #pragma unroll
    for (int o = 32; o; o >>= 1) s += __shfl_xor(s, o);
    float mean = s * (1.f / 512.f);
    float q = 0.f;
    #pragma unroll
    for (int j = 0; j < 8; j++) { float d = v[j] - mean; q += d * d; }
    #pragma unroll
    for (int o = 32; o; o >>= 1) q += __shfl_xor(q, o);
    float sd  = sqrtf(q * (1.f / 511.f));
    float inv = 1.f / (sd + 1e-6f);
    #pragma unroll
    for (int j = 0; j < 8; j++) {
        int c = lane + 64 * j;
        float val = g[c] * (v[j] - mean) * inv + bb[c];
        ushort_t h = f2bf_rne(val);
        float hf = __uint_as_float(((unsigned)h) << 16);
        long idx = (long)row * H_ + c;
        outH[idx] = h;
        outL[idx] = f2bf_rne(val - hf);
    }
}

// ---------------------------------------------------------------------------
// Attention v2 (unchanged from r7), fp32, LDS-b128 vectorized.
// ---------------------------------------------------------------------------
__global__ __launch_bounds__(256) void attn_kernel(
    const float* __restrict__ qkv, ushort_t* __restrict__ ctxH,
    ushort_t* __restrict__ ctxL)
{
    __shared__ __attribute__((aligned(16))) float qs[L_ * ATS];        // 19312 B
    __shared__ __attribute__((aligned(16))) float ks[(L_ + 1) * ATS];  // 19584 B (V reuses)
    __shared__ __attribute__((aligned(16))) float Ss[L_ * SST];        // 20448 B
    __shared__ float rsum[L_ + 1];
    const int tid = threadIdx.x;
    const int b = blockIdx.x >> 3, h = blockIdx.x & 7;
    const long qbase = (long)b * L_ * 1536 + h * DK_;

    // ---- stage Q,K (float4); zero K row 71 ----
    for (int idx = tid; idx < L_ * 16; idx += 256) {
        const int i = idx >> 4, s4 = idx & 15;
        const float4 qv = *(const float4*)(qkv + qbase + (long)i * 1536 + 4 * s4);
        const float4 kv = *(const float4*)(qkv + qbase + 512 + (long)i * 1536 + 4 * s4);
        *(float4*)(qs + i * ATS + 4 * s4) = qv;
        *(float4*)(ks + i * ATS + 4 * s4) = kv;
    }
    if (tid < 16) {
        float4 zz = {0.f, 0.f, 0.f, 0.f};
        *(float4*)(ks + 71 * ATS + 4 * tid) = zz;
    }
    __syncthreads();

    // ---- QK^T: 18 j-quads x 71 rows = 1278 items ----
    for (int item = tid; item < 18 * L_; item += 256) {
        const int jq = item / 71, i = item - jq * 71;
        const float* qr = qs + i * ATS;
        const float* k0 = ks + (4 * jq) * ATS;
        float s0 = 0.f, s1 = 0.f, s2 = 0.f, s3 = 0.f;
        #pragma unroll
        for (int s4 = 0; s4 < 16; s4++) {
            const float4 qv = *(const float4*)(qr + 4 * s4);
            const float4 k0v = *(const float4*)(k0 + 4 * s4);
            const float4 k1v = *(const float4*)(k0 + ATS + 4 * s4);
            const float4 k2v = *(const float4*)(k0 + 2 * ATS + 4 * s4);
            const float4 k3v = *(const float4*)(k0 + 3 * ATS + 4 * s4);
            s0 += qv.x * k0v.x + qv.y * k0v.y + qv.z * k0v.z + qv.w * k0v.w;
            s1 += qv.x * k1v.x + qv.y * k1v.y + qv.z * k1v.z + qv.w * k1v.w;
            s2 += qv.x * k2v.x + qv.y * k2v.y + qv.z * k2v.z + qv.w * k2v.w;
            s3 += qv.x * k3v.x + qv.y * k3v.y + qv.z * k3v.z + qv.w * k3v.w;
        }
        float4 sv; sv.x = s0; sv.y = s1; sv.z = s2; sv.w = s3;
        *(float4*)(Ss + i * SST + 4 * jq) = sv;
    }
    __syncthreads();

    // ---- re-stage V into ks (rows 0..70; row 71 stays zero) ----
    for (int idx = tid; idx < L_ * 16; idx += 256) {
        const int i = idx >> 4, s4 = idx & 15;
        *(float4*)(ks + i * ATS + 4 * s4) =
            *(const float4*)(qkv + qbase + 1024 + (long)i * 1536 + 4 * s4);
    }

    // ---- softmax: 4 lanes per row; rows {g, g+64}; deferred normalization ----
    {
        const int g = tid >> 2, r = tid & 3;
        #pragma unroll
        for (int half = 0; half < 2; half++) {
            const int row = g + half * 64;
            if (row < L_) {
                float4 vals[5];
                float mx = -1e30f;
                #pragma unroll
                for (int t = 0; t < 5; t++) {
                    const int q = r + 4 * t;
                    if (q < 18) {
                        float4 v = *(const float4*)(Ss + row * SST + 4 * q);
                        if (q == 17) v.w = -1e30f;   // j = 71 pad
                        vals[t] = v;
                        mx = fmaxf(mx, fmaxf(fmaxf(v.x, v.y), fmaxf(v.z, v.w)));
                    }
                }
                mx = fmaxf(mx, __shfl_xor(mx, 1));
                mx = fmaxf(mx, __shfl_xor(mx, 2));
                float sm = 0.f;
                #pragma unroll
                for (int t = 0; t < 5; t++) {
                    const int q = r + 4 * t;
                    if (q < 18) {
                        float4 v = vals[t];
                        v.x = expf(v.x - mx); v.y = expf(v.y - mx);
                        v.z = expf(v.z - mx); v.w = expf(v.w - mx);
                        sm += v.x + v.y + v.z + v.w;
                        *(float4*)(Ss + row * SST + 4 * q) = v;
                    }
                }
                sm += __shfl_xor(sm, 1);
                sm += __shfl_xor(sm, 2);
                if (r == 0) rsum[row] = 1.f / sm;
            }
        }
    }
    __syncthreads();

    // ---- PV: item (i,dq) -> ctx[i][4dq..+3] ----
    const long obase = (long)b * L_ * H_ + h * DK_;
    for (int item = tid; item < L_ * 16; item += 256) {
        const int i = item >> 4, dq = item & 15;
        const float* sr = Ss + i * SST;
        float ax = 0.f, ay = 0.f, az = 0.f, aw = 0.f;
        #pragma unroll
        for (int jq = 0; jq < 18; jq++) {
            const float4 sv = *(const float4*)(sr + 4 * jq);
            const float* v0 = ks + (4 * jq) * ATS + 4 * dq;
            const float4 va = *(const float4*)(v0);
            const float4 vb = *(const float4*)(v0 + ATS);
            const float4 vc = *(const float4*)(v0 + 2 * ATS);
            const float4 vd = *(const float4*)(v0 + 3 * ATS);
            ax += sv.x * va.x + sv.y * vb.x + sv.z * vc.x + sv.w * vd.x;
            ay += sv.x * va.y + sv.y * vb.y + sv.z * vc.y + sv.w * vd.y;
            az += sv.x * va.z + sv.y * vb.z + sv.z * vc.z + sv.w * vd.z;
            aw += sv.x * va.w + sv.y * vb.w + sv.z * vc.w + sv.w * vd.w;
        }
        const float rs = rsum[i];
        float o[4] = {ax * rs, ay * rs, az * rs, aw * rs};
        ushort4v hv, lv;
        #pragma unroll
        for (int c = 0; c < 4; c++) {
            ushort_t hh = f2bf_rne(o[c]);
            float hf = __uint_as_float(((unsigned)hh) << 16);
            hv[c] = hh;
            lv[c] = f2bf_rne(o[c] - hf);
        }
        const long oo = obase + (long)i * H_ + 4 * dq;
        *(ushort4v*)(ctxH + oo) = hv;
        *(ushort4v*)(ctxL + oo) = lv;
    }
}

// Embedding -> bf16 hi/lo planes
__global__ __launch_bounds__(256) void embed_kernel(
    const int* __restrict__ story, const int* __restrict__ query,
    const float* __restrict__ emb, const float* __restrict__ mask,
    ushort_t* __restrict__ xH, ushort_t* __restrict__ xL)
{
    __shared__ int idx[11];
    const int row = blockIdx.x;
    const int b = row / 71, m = row % 71;
    const int tid = threadIdx.x;
    if (tid < 11)
        idx[tid] = (m < 70) ? story[((long)b * 70 + m) * 11 + tid]
                            : query[(long)b * 11 + tid];
    __syncthreads();
    for (int c = tid; c < H_; c += 256) {
        float acc = 0.f;
        #pragma unroll
        for (int s = 0; s < 11; s++)
            acc += emb[(long)idx[s] * H_ + c] * mask[s * H_ + c];
        ushort_t h = f2bf_rne(acc);
        float hf = __uint_as_float(((unsigned)h) << 16);
        long o = (long)row * H_ + c;
        xH[o] = h;
        xL[o] = f2bf_rne(acc - hf);
    }
}

// transpose + scale + split fp32 [R,C] -> bf16 hi/lo planes rows rowOff.., ld=R
__global__ __launch_bounds__(256) void wsplitT_kernel(
    const float* __restrict__ in, ushort_t* __restrict__ hi, ushort_t* __restrict__ lo,
    int R, int C, int rowOff, float scale)
{
    long i = (long)blockIdx.x * 256 + threadIdx.x;
    if (i < (long)R * C) {
        int r = (int)(i / C), c = (int)(i % C);
        float f = in[i] * scale;
        ushort_t h = f2bf_rne(f);
        float hf = __uint_as_float(((unsigned)h) << 16);
        hi[(long)(c + rowOff) * R + r] = h;
        lo[(long)(c + rowOff) * R + r] = f2bf_rne(f - hf);
    }
}

// conv weight gather+split: plane[n*(3C) + d*C + c] = w[(n*C + c)*3 + d]
__global__ __launch_bounds__(256) void convw_split_kernel(
    const float* __restrict__ w, ushort_t* __restrict__ hi, ushort_t* __restrict__ lo,
    int N, int C)
{
    long i = (long)blockIdx.x * 256 + threadIdx.x;
    if (i < (long)N * C * 3) {
        int n = (int)(i / (3 * C));
        int r = (int)(i % (3 * C));
        int d = r / C, c = r % C;
        float f = w[((long)n * C + c) * 3 + d];
        ushort_t h = f2bf_rne(f);
        float hf = __uint_as_float(((unsigned)h) << 16);
        hi[i] = h;
        lo[i] = f2bf_rne(f - hf);
    }
}

// plain split: emb [V,E] -> hi/lo planes same layout
__global__ __launch_bounds__(256) void esplit_kernel(
    const float* __restrict__ in, ushort_t* __restrict__ hi, ushort_t* __restrict__ lo,
    long n)
{
    long i = (long)blockIdx.x * 256 + threadIdx.x;
    if (i < n) {
        float f = in[i];
        ushort_t h = f2bf_rne(f);
        float hf = __uint_as_float(((unsigned)h) << 16);
        hi[i] = h;
        lo[i] = f2bf_rne(f - hf);
    }
}

__global__ __launch_bounds__(256) void zero_f32(float* __restrict__ p, long n)
{
    long i = (long)blockIdx.x * 256 + threadIdx.x;
    if (i < n) p[i] = 0.f;
}

// pooled[b,c] = (sum_l prev[b,l,c]) / 71 -> bf16 hi/lo planes
__global__ __launch_bounds__(256) void pooled_kernel(
    const float* __restrict__ prev, ushort_t* __restrict__ pH, ushort_t* __restrict__ pL)
{
    int i = blockIdx.x * 256 + threadIdx.x;   // [0, 256*512)
    int b = i >> 9, c = i & 511;
    float s = 0.f;
    for (int l = 0; l < L_; l++) s += prev[((long)b * L_ + l) * H_ + c];
    float p = s / 71.0f;
    ushort_t h = f2bf_rne(p);
    float hf = __uint_as_float(((unsigned)h) << 16);
    pH[i] = h;
    pL[i] = f2bf_rne(p - hf);
}

__global__ __launch_bounds__(256) void softmax_kernel(
    const float* __restrict__ ah, float* __restrict__ out)
{
    __shared__ float red[256];
    const int b = blockIdx.x, tid = threadIdx.x;
    const float* a = ah + (long)b * V_;
    float mx = -1e30f;
    for (int i = tid; i < V_; i += 256) mx = fmaxf(mx, a[i]);
    red[tid] = mx; __syncthreads();
    for (int o = 128; o; o >>= 1) { if (tid < o) red[tid] = fmaxf(red[tid], red[tid + o]); __syncthreads(); }
    mx = red[0]; __syncthreads();
    float s = 0.f;
    for (int i = tid; i < V_; i += 256) s += expf(a[i] - mx);
    red[tid] = s; __syncthreads();
    for (int o = 128; o; o >>= 1) { if (tid < o) red[tid] += red[tid + o]; __syncthreads(); }
    float inv = 1.f / red[0];
    float* o_ = out + (long)b * V_;
    for (int i = tid; i < V_; i += 256) o_[i] = expf(a[i] - mx) * inv;
}

__global__ __launch_bounds__(256) void tails_kernel(
    const float* __restrict__ rem, const float* __restrict__ nu, float* __restrict__ out)
{
    int i = blockIdx.x * 256 + threadIdx.x;
    if (i < M_) {
        out[i] = rem[i];
        out[M_ + i] = nu[i];
    }
}

// ---------------------------------------------------------------------------
extern "C" void kernel_launch(void* const* d_in, const int* in_sizes, int n_in,
                              void* d_out, int out_size, void* d_ws, size_t ws_size,
                              hipStream_t stream)
{
    const int*   story  = (const int*)d_in[0];
    const int*   query  = (const int*)d_in[1];
    const float* emb    = (const float*)d_in[2];
    const float* mask_p = (const float*)d_in[3];
    const float* proj_w = (const float*)d_in[4];
    const float* ln1_g  = (const float*)d_in[5];
    const float* ln1_b  = (const float*)d_in[6];
    const float* wq     = (const float*)d_in[7];
    const float* wk     = (const float*)d_in[8];
    const float* wv     = (const float*)d_in[9];
    const float* wo     = (const float*)d_in[10];
    const float* c1_w   = (const float*)d_in[11];
    const float* c1_b   = (const float*)d_in[12];
    const float* c2_w   = (const float*)d_in[13];
    const float* c2_b   = (const float*)d_in[14];
    const float* ln2_g  = (const float*)d_in[15];
    const float* ln2_b  = (const float*)d_in[16];
    const float* p_w    = (const float*)d_in[17];
    const float* p_b    = (const float*)d_in[18];
    const float* out_b  = (const float*)d_in[19];
    float* outp = (float*)d_out;

    char* wsb = (char*)d_ws;
    size_t off = 0;
    auto alloc = [&](size_t bytes) -> void* {
        void* p = wsb + off;
        off = (off + bytes + 255) & ~(size_t)255;
        return p;
    };
    const long ROWE = (long)M_ * H_;             // 9,306,112 elements

    float* trunkF = (float*)alloc(ROWE * 4);
    float* prevF  = (float*)alloc(ROWE * 4);
    char*  poolC  = (char*)alloc(4L * ROWE * 4); // 148.9 MB multi-purpose pool
    float* hpF    = (float*)alloc((long)M_ * 4 * 4 + 64);
    float* remF   = hpF + M_;
    float* nuF    = hpF + 2 * M_;
    float* uwF    = hpF + 3 * M_;
    int*   flags  = (int*)(hpF + 4 * M_);
    ushort_t* projH = (ushort_t*)alloc((long)H_ * H_ * 2);
    ushort_t* projL = (ushort_t*)alloc((long)H_ * H_ * 2);
    ushort_t* wqkvH = (ushort_t*)alloc((long)3 * H_ * H_ * 2);
    ushort_t* wqkvL = (ushort_t*)alloc((long)3 * H_ * H_ * 2);
    ushort_t* woH   = (ushort_t*)alloc((long)H_ * H_ * 2);
    ushort_t* woL   = (ushort_t*)alloc((long)H_ * H_ * 2);
    ushort_t* W1H   = (ushort_t*)alloc((long)FS_ * 3 * H_ * 2);
    ushort_t* W1L   = (ushort_t*)alloc((long)FS_ * 3 * H_ * 2);
    ushort_t* W2H   = (ushort_t*)alloc((long)H_ * 3 * FS_ * 2);
    ushort_t* W2L   = (ushort_t*)alloc((long)H_ * 3 * FS_ * 2);
    ushort_t* pooledH = (ushort_t*)alloc((long)B_ * H_ * 2);
    ushort_t* pooledL = (ushort_t*)alloc((long)B_ * H_ * 2);
    float* Ttab     = (float*)alloc((long)L_ * H_ * 4);
    float* Ptab     = (float*)alloc(6L * H_ * 4);

    // pool aliases (phases disjoint in time):
    ushort_t* xnH = (ushort_t*)poolC;
    ushort_t* xnL = xnH + ROWE;
    float* qkvF = (float*)(poolC + ROWE * 4);            // 3*ROWE floats
    ushort_t* ctxH = xnH;
    ushort_t* ctxL = xnL;
    ushort_t* xn2H = (ushort_t*)poolC;
    ushort_t* xn2L = xn2H + ROWE;
    ushort_t* y1H  = (ushort_t*)(poolC + ROWE * 4);
    ushort_t* y1L  = y1H + (long)MH_ * FS_;
    float* partF   = (float*)(poolC + ROWE * 4 + (long)MH_ * FS_ * 4);  // 2 x MH_*H_ f32
    ushort_t* xembH = (ushort_t*)poolC;
    ushort_t* xembL = xembH + ROWE;
    ushort_t* embH = (ushort_t*)poolC;
    ushort_t* embL = embH + (long)V_ * H_;

    dim3 blk(256);
    dim3 blk128(128);

    // --- init (ws re-poisoned every call) ---
    zero_f32<<<dim3((unsigned)((ROWE + 255) / 256)), blk, 0, stream>>>(prevF, ROWE);
    zero_f32<<<dim3((3 * M_ + 255) / 256), blk, 0, stream>>>(hpF, 3 * M_);
    zero_f32<<<dim3(1), blk, 0, stream>>>((float*)flags, 16);
    sig_prep<<<dim3(154), blk, 0, stream>>>(Ttab, Ptab);

    // --- weight prep: transpose + hi/lo split (q-scale 1/8 folded, bit-exact) ---
    wsplitT_kernel<<<dim3(1024), blk, 0, stream>>>(proj_w, projH, projL, H_, H_, 0, 1.f);
    wsplitT_kernel<<<dim3(1024), blk, 0, stream>>>(wq, wqkvH, wqkvL, H_, H_, 0, 0.125f);
    wsplitT_kernel<<<dim3(1024), blk, 0, stream>>>(wk, wqkvH, wqkvL, H_, H_, 512, 1.f);
    wsplitT_kernel<<<dim3(1024), blk, 0, stream>>>(wv, wqkvH, wqkvL, H_, H_, 1024, 1.f);
    wsplitT_kernel<<<dim3(1024), blk, 0, stream>>>(wo, woH, woL, H_, H_, 0, 1.f);
    convw_split_kernel<<<dim3(12288), blk, 0, stream>>>(c1_w, W1H, W1L, FS_, H_);
    convw_split_kernel<<<dim3(12288), blk, 0, stream>>>(c2_w, W2H, W2L, H_, FS_);

    // --- embedding + input projection ---
    embed_kernel<<<dim3(M_), blk, 0, stream>>>(story, query, emb, mask_p, xembH, xembL);
    gemm_s<64><<<dim3(H_ / 64, M_ / 128), blk, 0, stream>>>(
        xembH, xembL, H_, 0, projH, projL, H_, H_,
        nullptr, nullptr, 1.f, 0, 0, trunkF, nullptr, nullptr);

    // --- ACT loop: 6 steps with faithful any()-gate ---
    for (int t = 0; t < 6; t++) {
        gate_kernel<<<dim3(M_ / 256), blk, 0, stream>>>(hpF, nuF, flags + t);
        s_pr_kernel<<<dim3(M_ / 4), blk, 0, stream>>>(trunkF, Ttab, Ptab, p_w, p_b,
                                                      hpF, remF, nuF, uwF, flags + t, t);
        ln_kernel<<<dim3(M_ / 4), blk, 0, stream>>>(trunkF, ln1_g, ln1_b, xnH, xnL);
        gemm_s<128><<<dim3(1536 / 128, M_ / 128), blk, 0, stream>>>(
            xnH, xnL, H_, 0, wqkvH, wqkvL, 1536, H_,
            nullptr, nullptr, 1.f, 0, 0, qkvF, nullptr, nullptr);
        attn_kernel<<<dim3(B_ * NH_), blk, 0, stream>>>(qkvF, ctxH, ctxL);
        gemm_s<64><<<dim3(H_ / 64, M_ / 128), blk, 0, stream>>>(
            ctxH, ctxL, H_, 0, woH, woL, H_, H_,
            nullptr, trunkF, 1.f, 0, 0, trunkF, nullptr, nullptr);
        ln_kernel<<<dim3(M_ / 4), blk, 0, stream>>>(trunkF, ln2_g, ln2_b, xn2H, xn2L);
        for (int half = 0; half < 2; half++) {
            int ro = half * MH_;
            gemm_conv<0><<<dim3(2272), blk128, 0, stream>>>(
                xn2H, xn2L, H_, ro, ro, W1H, W1L, FS_,
                c1_b, y1H, y1L, nullptr, 0, 512);
            gemm_conv<1><<<dim3(1136), blk128, 0, stream>>>(
                y1H, y1L, FS_, 0, ro, W2H, W2L, H_,
                nullptr, nullptr, nullptr, partF, (long)MH_ * H_, 1024);
            conv2_reduce<<<dim3((unsigned)((long)MH_ * H_ / 4 / 256)), blk, 0, stream>>>(
                partF, (long)MH_ * H_, c2_b, trunkF, prevF, uwF, ro);
        }
    }

    // --- output head ---
    pooled_kernel<<<dim3(B_ * H_ / 256), blk, 0, stream>>>(prevF, pooledH, pooledL);
    esplit_kernel<<<dim3(64000), blk, 0, stream>>>(emb, embH, embL, (long)V_ * H_);
    gemm_s<64><<<dim3(V_ / 64, B_ / 128), blk, 0, stream>>>(
        pooledH, pooledL, H_, 0, embH, embL, V_, H_,
        out_b, nullptr, 1.f, 0, 0, outp, nullptr, nullptr);
    softmax_kernel<<<dim3(B_), blk, 0, stream>>>(outp, outp + (long)B_ * V_);
    tails_kernel<<<dim3((M_ + 255) / 256), blk, 0, stream>>>(remF, nuF, outp + 2L * B_ * V_);
}